// Round 1
// 151.003 us; speedup vs baseline: 1.1245x; 1.1245x over previous
//
#include <hip/hip_runtime.h>
#include <math.h>

#define D_MODEL 768
#define NUM_HEADS 12
#define D_K 64
#define B_SZ 2
#define S_LEN 2048
#define M_TOT (B_SZ * S_LEN)          // 4096
#define OUT0 (M_TOT * D_MODEL)        // 3145728 floats
#define BH (B_SZ * NUM_HEADS)         // 24
#define WSZ ((size_t)D_MODEL * D_MODEL)
#define PSZ ((size_t)M_TOT * D_MODEL)

// swizzled LDS byte offset within a 128B-stride row tile
#define SWZ(row, off) ((row) * 128 + ((off) ^ (((row) & 7) << 4)))

typedef __attribute__((ext_vector_type(8))) short s16x8;
typedef __attribute__((ext_vector_type(4))) short s16x4;
typedef __attribute__((ext_vector_type(4))) float f32x4;
typedef __attribute__((ext_vector_type(2))) unsigned u32x2;

__device__ __forceinline__ short f2bf(float f) {
    union { float f; unsigned u; } x; x.f = f;
    unsigned r = x.u + 0x7fffu + ((x.u >> 16) & 1u);
    return (short)(r >> 16);
}

// bare v_exp_f32 (2^x) — scale 0.125*log2(e) is pre-folded into W_q
__device__ __forceinline__ float fexp2(float x) {
#if __has_builtin(__builtin_amdgcn_exp2f)
    return __builtin_amdgcn_exp2f(x);
#else
    float r; asm("v_exp_f32 %0, %1" : "=v"(r) : "v"(x)); return r;
#endif
}

// async global->LDS, 16B per lane (m97 staging primitive)
__device__ __forceinline__ void gload16(const void* g, void* l) {
    __builtin_amdgcn_global_load_lds(
        (const __attribute__((address_space(1))) unsigned int*)g,
        (__attribute__((address_space(3))) unsigned int*)l, 16, 0, 0);
}

// ---------------------------------------------------------------------------
// cvt_all: one launch covering (a) q/k/v fp32->bf16 slabs (blocks 0..4607),
// (b) weight convert+transpose Wt[z][n][k] (blocks 4608..5183; z==0 folds
// the 0.125 attention scale AND log2(e) into W_q so softmax uses raw v_exp).
// ---------------------------------------------------------------------------
__global__ void cvt_all(const float* __restrict__ q, const float* __restrict__ k,
                        const float* __restrict__ v, short* __restrict__ Xb,
                        const float* __restrict__ W0, const float* __restrict__ W1,
                        const float* __restrict__ W2, const float* __restrict__ W3,
                        short* __restrict__ Wt) {
    const int bx = blockIdx.x;
    const int t = threadIdx.x;
    if (bx < 4608) {
        const int z = bx / 1536, blk = bx - z * 1536;
        const float* src = z == 0 ? q : z == 1 ? k : v;
        const size_t base = ((size_t)blk * 256 + t) * 8;
        float4 v0 = *(const float4*)(src + base);
        float4 v1 = *(const float4*)(src + base + 4);
        s16x8 o;
        o[0] = f2bf(v0.x); o[1] = f2bf(v0.y); o[2] = f2bf(v0.z); o[3] = f2bf(v0.w);
        o[4] = f2bf(v1.x); o[5] = f2bf(v1.y); o[6] = f2bf(v1.z); o[7] = f2bf(v1.w);
        *(s16x8*)(Xb + (size_t)z * PSZ + base) = o;
    } else {
        __shared__ short Ts[64][65];
        const int u = bx - 4608;
        const int z = u / 144, vv = u - z * 144;
        const float* W = z == 0 ? W0 : z == 1 ? W1 : z == 2 ? W2 : W3;
        // 0.125 * log2(e): softmax exp(s) becomes exp2(s') with s' pre-scaled
        const float sc = (z == 0) ? 0.18033688011112042f : 1.0f;
        short* dst = Wt + (size_t)z * WSZ;
        const int k0 = (vv / 12) * 64, n0 = (vv % 12) * 64;
#pragma unroll
        for (int e = 0; e < 16; ++e) {
            int uu = t + 256 * e; int r = uu >> 6, c = uu & 63;
            Ts[c][r] = f2bf(sc * W[(size_t)(k0 + r) * D_MODEL + n0 + c]);
        }
        __syncthreads();
#pragma unroll
        for (int e = 0; e < 16; ++e) {
            int uu = t + 256 * e; int r = uu >> 6, c = uu & 63;
            dst[(size_t)(n0 + r) * D_MODEL + k0 + c] = Ts[r][c];
        }
    }
}

// ---------------------------------------------------------------------------
// QKV GEMM (R8 reg-staged flavor): Y = X @ Wt^T, bf16 MFMA,
// 128x128 tile, BK=64, swizzled LDS. z=0,1: bf16 split-head slabs (Q,K).
// z=2: V written DIRECTLY in Vt layout [bh][dk][s].
// ---------------------------------------------------------------------------
__global__ void proj128(const short* __restrict__ Xb, const short* __restrict__ Wt,
                        short* __restrict__ Yv, short* __restrict__ Vt) {
    __shared__ __align__(16) char As[16384];
    __shared__ __align__(16) char Bs[16384];
    const int t = threadIdx.x, lane = t & 63, w = t >> 6;
    const int l15 = lane & 15, lg = lane >> 4;
    const int wr = w >> 1, wc = w & 1;
    const int m0 = blockIdx.x * 128, n0 = blockIdx.y * 128;
    const int z = blockIdx.z;
    const short* X = Xb + (size_t)z * PSZ;
    const short* W = Wt + (size_t)z * WSZ;

    f32x4 acc[4][4] = {};
    for (int k0 = 0; k0 < D_MODEL; k0 += 64) {
        __syncthreads();
#pragma unroll
        for (int e = 0; e < 4; ++e) {
            int u = t + 256 * e, row = u >> 3, c8 = u & 7;
            s16x8 va = *(const s16x8*)(X + (size_t)(m0 + row) * D_MODEL + k0 + c8 * 8);
            *(s16x8*)(As + SWZ(row, c8 * 16)) = va;
            s16x8 vb = *(const s16x8*)(W + (size_t)(n0 + row) * D_MODEL + k0 + c8 * 8);
            *(s16x8*)(Bs + SWZ(row, c8 * 16)) = vb;
        }
        __syncthreads();
#pragma unroll
        for (int kk = 0; kk < 2; ++kk) {
            const int kb = kk * 64 + lg * 16;
            s16x8 a[4], b[4];
#pragma unroll
            for (int i = 0; i < 4; ++i) {
                int ra = wr * 64 + i * 16 + l15;
                a[i] = *(const s16x8*)(As + SWZ(ra, kb));
                int rb = wc * 64 + i * 16 + l15;
                b[i] = *(const s16x8*)(Bs + SWZ(rb, kb));
            }
#pragma unroll
            for (int i = 0; i < 4; ++i)
#pragma unroll
                for (int j = 0; j < 4; ++j)
                    acc[i][j] = __builtin_amdgcn_mfma_f32_16x16x32_bf16(a[i], b[j], acc[i][j], 0, 0, 0);
        }
    }

    if (z < 2) {
#pragma unroll
        for (int i = 0; i < 4; ++i)
#pragma unroll
            for (int j = 0; j < 4; ++j)
#pragma unroll
                for (int r = 0; r < 4; ++r) {
                    int m = m0 + wr * 64 + i * 16 + lg * 4 + r;
                    int n = n0 + wc * 64 + j * 16 + l15;
                    int b_ = m >> 11, s = m & (S_LEN - 1);
                    int h = n >> 6, dk = n & 63;
                    Yv[(size_t)z * PSZ +
                       (((size_t)(b_ * NUM_HEADS + h) * S_LEN + s) * D_K + dk)] = f2bf(acc[i][j][r]);
                }
    } else {
        // V: write Vt[bh][dk][s]; 4 consecutive s per fragment -> 8B stores
#pragma unroll
        for (int i = 0; i < 4; ++i)
#pragma unroll
            for (int j = 0; j < 4; ++j) {
                int m = m0 + wr * 64 + i * 16 + lg * 4;   // 4 consecutive s
                int n = n0 + wc * 64 + j * 16 + l15;
                int b_ = m >> 11, s = m & (S_LEN - 1);
                int h = n >> 6, dk = n & 63;
                s16x4 pack;
#pragma unroll
                for (int r = 0; r < 4; ++r) pack[r] = f2bf(acc[i][j][r]);
                *(s16x4*)(Vt + ((size_t)(b_ * NUM_HEADS + h) * D_K + dk) * S_LEN + s) = pack;
            }
    }
}

// ---------------------------------------------------------------------------
// O-projection: 64x64 tile -> 768 blocks (3/CU). out = AO @ Wo^T + bias.
// gload_lds staging into linear LDS. Final out stores are nontemporal
// (never re-read; keep L2 clean).
// ---------------------------------------------------------------------------
__global__ void proj64o(const short* __restrict__ AO, const short* __restrict__ Wt,
                        const float* __restrict__ bias, float* __restrict__ out) {
    __shared__ __align__(16) char As[8192];   // [64][64] bf16 linear
    __shared__ __align__(16) char Bs[8192];
    const int t = threadIdx.x, lane = t & 63, w = t >> 6;
    const int l15 = lane & 15, lg = lane >> 4;
    const int wr = w >> 1, wc = w & 1;
    const int m0 = blockIdx.x * 64, n0 = blockIdx.y * 64;

    const int r8 = t >> 3, c8 = (t & 7) * 8;   // 256 units of 16B cover 32 rows
    f32x4 acc[2][2] = {};
    for (int k0 = 0; k0 < D_MODEL; k0 += 64) {
        __syncthreads();
        {
            gload16(AO + (size_t)(m0 + r8) * D_MODEL + k0 + c8, As + t * 16);
            gload16(AO + (size_t)(m0 + 32 + r8) * D_MODEL + k0 + c8, As + (t + 256) * 16);
            gload16(Wt + (size_t)(n0 + r8) * D_MODEL + k0 + c8, Bs + t * 16);
            gload16(Wt + (size_t)(n0 + 32 + r8) * D_MODEL + k0 + c8, Bs + (t + 256) * 16);
        }
        __syncthreads();
#pragma unroll
        for (int kk = 0; kk < 2; ++kk) {
            const int kb = kk * 64 + lg * 16;
            s16x8 a[2], b[2];
#pragma unroll
            for (int i = 0; i < 2; ++i) {
                a[i] = *(const s16x8*)(As + (wr * 32 + i * 16 + l15) * 128 + kb);
                b[i] = *(const s16x8*)(Bs + (wc * 32 + i * 16 + l15) * 128 + kb);
            }
#pragma unroll
            for (int i = 0; i < 2; ++i)
#pragma unroll
                for (int j = 0; j < 2; ++j)
                    acc[i][j] = __builtin_amdgcn_mfma_f32_16x16x32_bf16(a[i], b[j], acc[i][j], 0, 0, 0);
        }
    }
#pragma unroll
    for (int i = 0; i < 2; ++i)
#pragma unroll
        for (int j = 0; j < 2; ++j)
#pragma unroll
            for (int r = 0; r < 4; ++r) {
                int m = m0 + wr * 32 + i * 16 + lg * 4 + r;
                int n = n0 + wc * 32 + j * 16 + l15;
                __builtin_nontemporal_store(acc[i][j][r] + bias[n],
                                            out + (size_t)m * D_MODEL + n);
            }
}

// ---------------------------------------------------------------------------
// Fused attention — R18 winner + this round:
//  * exp2-folded softmax: W_q carries 0.125*log2(e); pass-1/2 use bare
//    v_exp_f32; pass-2 folds -log2(Z) into the MFMA C-input (normalization
//    is free — no invZ muls).
//  * pass-1 Z accumulated in f32x4 (breaks the 512-deep serial fadd chain).
//  * attn prob stores are NONTEMPORAL: the 403MB write stream no longer
//    allocates in L2, protecting K/V (and AO) residency per XCD.
// ---------------------------------------------------------------------------
#define KS(c) (SMEM + (c) * 8192)
#define VS(c) (SMEM + 16384 + (c) * 8192)
#define PS    (SMEM + 32768)
#define KB(c) (SMEM + (c) * 16384)

__global__ __launch_bounds__(256, 4) void attn_fused(const short* __restrict__ Qp,
                                                     const short* __restrict__ Kp,
                                                     const short* __restrict__ Vt,
                                                     float* __restrict__ attn,
                                                     short* __restrict__ AO) {
    __shared__ __align__(16) char SMEM[40960];

    const int t = threadIdx.x, lane = t & 63, w = t >> 6;
    const int l15 = lane & 15, lg = lane >> 4;
    int wg = blockIdx.x;
    wg = (wg & 7) * 96 + (wg >> 3);   // XCD-chunked: 96 wgs (3 heads) per XCD
    const int q0 = (wg & 31) * 64;
    const int bh = wg >> 5;
    const int b_ = bh / NUM_HEADS, h = bh % NUM_HEADS;
    const short* Qg = Qp + (size_t)bh * S_LEN * D_K;
    const short* Kg = Kp + (size_t)bh * S_LEN * D_K;
    const short* Vg = Vt + (size_t)bh * D_K * S_LEN;
    float* attng = attn + (size_t)bh * S_LEN * S_LEN;
    char* Pw = PS + w * 2048;

    const int r0 = t >> 3, c0 = t & 7;          // this thread's staging slot 0
    const int r1 = (t + 256) >> 3, c1 = t & 7;  // slot 1 (rows 32..63)

    // Q fragments (B-operand) direct from global, invariant across kt
    const int qrow = w * 16 + l15;
    const s16x8 qa = *(const s16x8*)(Qg + (size_t)(q0 + qrow) * D_K + lg * 8);
    const s16x8 qb = *(const s16x8*)(Qg + (size_t)(q0 + qrow) * D_K + 32 + lg * 8);

    // ---- pass 1 prologue: stage K rows 0..127 into KB(0) ----
#pragma unroll
    for (int e = 0; e < 4; ++e) {
        int row = r0 + 32 * e;
        s16x8 kv = *(const s16x8*)(Kg + (size_t)row * D_K + c0 * 8);
        *(s16x8*)(KB(0) + SWZ(row, c0 * 16)) = kv;
    }
    __syncthreads();

    // ---- pass 1: Z = row sums of exp2(s'); BK=128, 16 barriers ----
    f32x4 zv = {};
    for (int kt2 = 0; kt2 < 16; ++kt2) {
        const int c = kt2 & 1;
        s16x8 nk[4];
        if (kt2 < 15) {
#pragma unroll
            for (int e = 0; e < 4; ++e)
                nk[e] = *(const s16x8*)(Kg + (size_t)((kt2 + 1) * 128 + r0 + 32 * e) * D_K + c0 * 8);
        }
#pragma unroll
        for (int sub = 0; sub < 2; ++sub)
#pragma unroll
            for (int mf = 0; mf < 4; ++mf) {
                int krow = sub * 64 + mf * 16 + l15;
                s16x8 ka = *(const s16x8*)(KB(c) + SWZ(krow, lg * 16));
                s16x8 kb = *(const s16x8*)(KB(c) + SWZ(krow, 64 + lg * 16));
                f32x4 s4 = {};
                s4 = __builtin_amdgcn_mfma_f32_16x16x32_bf16(ka, qa, s4, 0, 0, 0);
                s4 = __builtin_amdgcn_mfma_f32_16x16x32_bf16(kb, qb, s4, 0, 0, 0);
#pragma unroll
                for (int r = 0; r < 4; ++r) zv[r] += fexp2(s4[r]);
            }
        if (kt2 < 15) {
#pragma unroll
            for (int e = 0; e < 4; ++e)
                *(s16x8*)(KB(c ^ 1) + SWZ(r0 + 32 * e, c0 * 16)) = nk[e];
        }
        __syncthreads();
    }
    float z = (zv[0] + zv[1]) + (zv[2] + zv[3]);
    z += __shfl_xor(z, 16);
    z += __shfl_xor(z, 32);
    const float mlz = -__log2f(z);   // fold normalization into MFMA C-input

    // ---- pass 2 prologue: restage K0, V0 ----
    {
        s16x8 k0 = *(const s16x8*)(Kg + (size_t)r0 * D_K + c0 * 8);
        s16x8 k1 = *(const s16x8*)(Kg + (size_t)r1 * D_K + c1 * 8);
        s16x8 v0 = *(const s16x8*)(Vg + (size_t)r0 * S_LEN + c0 * 8);
        s16x8 v1 = *(const s16x8*)(Vg + (size_t)r1 * S_LEN + c1 * 8);
        *(s16x8*)(KS(0) + SWZ(r0, c0 * 16)) = k0;
        *(s16x8*)(KS(0) + SWZ(r1, c1 * 16)) = k1;
        *(s16x8*)(VS(0) + SWZ(r0, c0 * 16)) = v0;
        *(s16x8*)(VS(0) + SWZ(r1, c1 * 16)) = v1;
    }
    __syncthreads();

    f32x4 accO[4] = {};
    for (int kt = 0; kt < 32; ++kt) {
        const int c = kt & 1;
        s16x8 nk0, nk1, nv0, nv1;
        if (kt < 31) {
            nk0 = *(const s16x8*)(Kg + (size_t)((kt + 1) * 64 + r0) * D_K + c0 * 8);
            nk1 = *(const s16x8*)(Kg + (size_t)((kt + 1) * 64 + r1) * D_K + c1 * 8);
            nv0 = *(const s16x8*)(Vg + (size_t)r0 * S_LEN + (kt + 1) * 64 + c0 * 8);
            nv1 = *(const s16x8*)(Vg + (size_t)r1 * S_LEN + (kt + 1) * 64 + c1 * 8);
        }
        // QK^T -> probs (normalized via C-init) -> bf16 Pw (per-wave private)
#pragma unroll
        for (int mf = 0; mf < 4; ++mf) {
            int krow = mf * 16 + l15;
            s16x8 ka = *(const s16x8*)(KS(c) + SWZ(krow, lg * 16));
            s16x8 kb = *(const s16x8*)(KS(c) + SWZ(krow, 64 + lg * 16));
            f32x4 s4 = {mlz, mlz, mlz, mlz};
            s4 = __builtin_amdgcn_mfma_f32_16x16x32_bf16(ka, qa, s4, 0, 0, 0);
            s4 = __builtin_amdgcn_mfma_f32_16x16x32_bf16(kb, qb, s4, 0, 0, 0);
            float p0 = fexp2(s4[0]);
            float p1 = fexp2(s4[1]);
            float p2 = fexp2(s4[2]);
            float p3 = fexp2(s4[3]);
            unsigned pk0, pk1;
            asm("v_cvt_pk_bf16_f32 %0, %1, %2" : "=v"(pk0) : "v"(p0), "v"(p1));
            asm("v_cvt_pk_bf16_f32 %0, %1, %2" : "=v"(pk1) : "v"(p2), "v"(p3));
            u32x2 pw2 = {pk0, pk1};
            *(u32x2*)(Pw + SWZ(l15, mf * 32 + lg * 8)) = pw2;
        }
        asm volatile("s_waitcnt lgkmcnt(0)" ::: "memory");
        __builtin_amdgcn_sched_barrier(0);
        // coalesced prob stores: instr i covers rows i*4+lg; 16 lanes sweep a
        // full 256B row -> ~4 contiguous txns/instr. NONTEMPORAL: don't
        // allocate the 403MB stream in L2 (protect K/V residency).
#pragma unroll
        for (int i = 0; i < 4; ++i) {
            int row = i * 4 + lg;
            u32x2 pk = *(const u32x2*)(Pw + SWZ(row, l15 * 8));
            union { unsigned u; float f; } t0, t1, t2, t3;
            t0.u = pk[0] << 16;
            t1.u = pk[0] & 0xFFFF0000u;
            t2.u = pk[1] << 16;
            t3.u = pk[1] & 0xFFFF0000u;
            f32x4 pv = {t0.f, t1.f, t2.f, t3.f};
            __builtin_nontemporal_store(
                pv, (f32x4*)(attng + (size_t)(q0 + w * 16 + row) * S_LEN + kt * 64 + l15 * 4));
        }
        // PV: O[16q x 64d] += P[16q x 64k] @ V^T[64k x 64d]
#pragma unroll
        for (int ks = 0; ks < 2; ++ks) {
            s16x8 ap = *(const s16x8*)(Pw + SWZ(l15, ks * 64 + lg * 16));
#pragma unroll
            for (int df = 0; df < 4; ++df) {
                int vrow = df * 16 + l15;
                s16x8 bv = *(const s16x8*)(VS(c) + SWZ(vrow, ks * 64 + lg * 16));
                accO[df] = __builtin_amdgcn_mfma_f32_16x16x32_bf16(ap, bv, accO[df], 0, 0, 0);
            }
        }
        if (kt < 31) {
            *(s16x8*)(KS(c ^ 1) + SWZ(r0, c0 * 16)) = nk0;
            *(s16x8*)(KS(c ^ 1) + SWZ(r1, c1 * 16)) = nk1;
            *(s16x8*)(VS(c ^ 1) + SWZ(r0, c0 * 16)) = nv0;
            *(s16x8*)(VS(c ^ 1) + SWZ(r1, c1 * 16)) = nv1;
        }
        __syncthreads();
    }

#pragma unroll
    for (int df = 0; df < 4; ++df)
#pragma unroll
        for (int r = 0; r < 4; ++r) {
            int srow = q0 + w * 16 + lg * 4 + r;
            AO[((size_t)(b_ * S_LEN + srow)) * D_MODEL + h * D_K + df * 16 + l15] = f2bf(accO[df][r]);
        }
}

// ---------------------------------------------------------------------------
extern "C" void kernel_launch(void* const* d_in, const int* in_sizes, int n_in,
                              void* d_out, int out_size, void* d_ws, size_t ws_size,
                              hipStream_t stream) {
    const float* q = (const float*)d_in[0];
    const float* k = (const float*)d_in[1];
    const float* v = (const float*)d_in[2];
    const float* Wq = (const float*)d_in[3];
    const float* Wk = (const float*)d_in[4];
    const float* Wv = (const float*)d_in[5];
    const float* Wo = (const float*)d_in[6];
    const float* bo = (const float*)d_in[7];

    float* out = (float*)d_out;         // [B][S][D_MODEL] fp32
    float* attn = (float*)d_out + OUT0; // [B][H][S][S] fp32

    // bf16 q/k/v slabs live in the not-yet-written attn region of d_out
    // (18.9 MB << 403 MB; fully dead before attn_fused overwrites it).
    short* Xb = (short*)attn;

    short* wsS = (short*)d_ws;
    short* Wtq = wsS;            // 4 * WSZ  (Wq*0.125*log2e, Wk, Wv, Wo transposed bf16)
    short* Qp = Wtq + 4 * WSZ;   // 2 * PSZ  (Q,K split-head slabs)
    short* Kp = Qp + PSZ;
    short* Vtg = Kp + PSZ;       // PSZ  (V directly in [bh][dk][s] layout)
    short* AO = Vtg + PSZ;       // PSZ

    dim3 blk(256);

    cvt_all<<<dim3(5184), blk, 0, stream>>>(q, k, v, Xb, Wq, Wk, Wv, Wo, Wtq);

    proj128<<<dim3(M_TOT / 128, D_MODEL / 128, 3), blk, 0, stream>>>(Xb, Wtq, Qp, Vtg);

    attn_fused<<<dim3(768), blk, 0, stream>>>(Qp, Kp, Vtg, attn, AO);

    proj64o<<<dim3(M_TOT / 64, D_MODEL / 64), blk, 0, stream>>>(AO, Wtq + 3 * WSZ, bo, out);
}

// Round 2
// 146.066 us; speedup vs baseline: 1.1625x; 1.0338x over previous
//
#include <hip/hip_runtime.h>
#include <math.h>

#define D_MODEL 768
#define NUM_HEADS 12
#define D_K 64
#define B_SZ 2
#define S_LEN 2048
#define M_TOT (B_SZ * S_LEN)          // 4096
#define OUT0 (M_TOT * D_MODEL)        // 3145728 floats
#define BH (B_SZ * NUM_HEADS)         // 24
#define WSZ ((size_t)D_MODEL * D_MODEL)
#define PSZ ((size_t)M_TOT * D_MODEL)

// swizzled LDS byte offset within a 128B-stride row tile
#define SWZ(row, off) ((row) * 128 + ((off) ^ (((row) & 7) << 4)))

typedef __attribute__((ext_vector_type(8))) short s16x8;
typedef __attribute__((ext_vector_type(4))) short s16x4;
typedef __attribute__((ext_vector_type(4))) float f32x4;
typedef __attribute__((ext_vector_type(2))) unsigned u32x2;

__device__ __forceinline__ short f2bf(float f) {
    union { float f; unsigned u; } x; x.f = f;
    unsigned r = x.u + 0x7fffu + ((x.u >> 16) & 1u);
    return (short)(r >> 16);
}

// bare v_exp_f32 (2^x) — scale 0.125*log2(e) is pre-folded into W_q
__device__ __forceinline__ float fexp2(float x) {
#if __has_builtin(__builtin_amdgcn_exp2f)
    return __builtin_amdgcn_exp2f(x);
#else
    float r; asm("v_exp_f32 %0, %1" : "=v"(r) : "v"(x)); return r;
#endif
}

// LDS-only barrier: orders ds ops across waves WITHOUT draining vmcnt,
// so the in-flight attn global stores keep retiring in the background
// (T4: never drain vmcnt to 0 in the main loop). sched_barrier pins
// ordering so hipcc can't hoist LDS ops past the inline-asm waitcnt.
__device__ __forceinline__ void ldsbar() {
    asm volatile("s_waitcnt lgkmcnt(0)" ::: "memory");
    __builtin_amdgcn_sched_barrier(0);
    __builtin_amdgcn_s_barrier();
    __builtin_amdgcn_sched_barrier(0);
}

// async global->LDS, 16B per lane (m97 staging primitive)
__device__ __forceinline__ void gload16(const void* g, void* l) {
    __builtin_amdgcn_global_load_lds(
        (const __attribute__((address_space(1))) unsigned int*)g,
        (__attribute__((address_space(3))) unsigned int*)l, 16, 0, 0);
}

// ---------------------------------------------------------------------------
// cvt_all: one launch covering (a) q/k/v fp32->bf16 slabs (blocks 0..4607),
// (b) weight convert+transpose Wt[z][n][k] (blocks 4608..5183; z==0 folds
// the 0.125 attention scale AND log2(e) into W_q so softmax uses raw v_exp).
// ---------------------------------------------------------------------------
__global__ void cvt_all(const float* __restrict__ q, const float* __restrict__ k,
                        const float* __restrict__ v, short* __restrict__ Xb,
                        const float* __restrict__ W0, const float* __restrict__ W1,
                        const float* __restrict__ W2, const float* __restrict__ W3,
                        short* __restrict__ Wt) {
    const int bx = blockIdx.x;
    const int t = threadIdx.x;
    if (bx < 4608) {
        const int z = bx / 1536, blk = bx - z * 1536;
        const float* src = z == 0 ? q : z == 1 ? k : v;
        const size_t base = ((size_t)blk * 256 + t) * 8;
        float4 v0 = *(const float4*)(src + base);
        float4 v1 = *(const float4*)(src + base + 4);
        s16x8 o;
        o[0] = f2bf(v0.x); o[1] = f2bf(v0.y); o[2] = f2bf(v0.z); o[3] = f2bf(v0.w);
        o[4] = f2bf(v1.x); o[5] = f2bf(v1.y); o[6] = f2bf(v1.z); o[7] = f2bf(v1.w);
        *(s16x8*)(Xb + (size_t)z * PSZ + base) = o;
    } else {
        __shared__ short Ts[64][65];
        const int u = bx - 4608;
        const int z = u / 144, vv = u - z * 144;
        const float* W = z == 0 ? W0 : z == 1 ? W1 : z == 2 ? W2 : W3;
        // 0.125 * log2(e): softmax exp(s) becomes exp2(s') with s' pre-scaled
        const float sc = (z == 0) ? 0.18033688011112042f : 1.0f;
        short* dst = Wt + (size_t)z * WSZ;
        const int k0 = (vv / 12) * 64, n0 = (vv % 12) * 64;
#pragma unroll
        for (int e = 0; e < 16; ++e) {
            int uu = t + 256 * e; int r = uu >> 6, c = uu & 63;
            Ts[c][r] = f2bf(sc * W[(size_t)(k0 + r) * D_MODEL + n0 + c]);
        }
        __syncthreads();
#pragma unroll
        for (int e = 0; e < 16; ++e) {
            int uu = t + 256 * e; int r = uu >> 6, c = uu & 63;
            dst[(size_t)(n0 + r) * D_MODEL + k0 + c] = Ts[r][c];
        }
    }
}

// ---------------------------------------------------------------------------
// QKV GEMM (R8 reg-staged flavor): Y = X @ Wt^T, bf16 MFMA,
// 128x128 tile, BK=64, swizzled LDS. z=0,1: bf16 split-head slabs (Q,K).
// z=2: V written DIRECTLY in Vt layout [bh][dk][s].
// ---------------------------------------------------------------------------
__global__ void proj128(const short* __restrict__ Xb, const short* __restrict__ Wt,
                        short* __restrict__ Yv, short* __restrict__ Vt) {
    __shared__ __align__(16) char As[16384];
    __shared__ __align__(16) char Bs[16384];
    const int t = threadIdx.x, lane = t & 63, w = t >> 6;
    const int l15 = lane & 15, lg = lane >> 4;
    const int wr = w >> 1, wc = w & 1;
    const int m0 = blockIdx.x * 128, n0 = blockIdx.y * 128;
    const int z = blockIdx.z;
    const short* X = Xb + (size_t)z * PSZ;
    const short* W = Wt + (size_t)z * WSZ;

    f32x4 acc[4][4] = {};
    for (int k0 = 0; k0 < D_MODEL; k0 += 64) {
        __syncthreads();
#pragma unroll
        for (int e = 0; e < 4; ++e) {
            int u = t + 256 * e, row = u >> 3, c8 = u & 7;
            s16x8 va = *(const s16x8*)(X + (size_t)(m0 + row) * D_MODEL + k0 + c8 * 8);
            *(s16x8*)(As + SWZ(row, c8 * 16)) = va;
            s16x8 vb = *(const s16x8*)(W + (size_t)(n0 + row) * D_MODEL + k0 + c8 * 8);
            *(s16x8*)(Bs + SWZ(row, c8 * 16)) = vb;
        }
        __syncthreads();
#pragma unroll
        for (int kk = 0; kk < 2; ++kk) {
            const int kb = kk * 64 + lg * 16;
            s16x8 a[4], b[4];
#pragma unroll
            for (int i = 0; i < 4; ++i) {
                int ra = wr * 64 + i * 16 + l15;
                a[i] = *(const s16x8*)(As + SWZ(ra, kb));
                int rb = wc * 64 + i * 16 + l15;
                b[i] = *(const s16x8*)(Bs + SWZ(rb, kb));
            }
#pragma unroll
            for (int i = 0; i < 4; ++i)
#pragma unroll
                for (int j = 0; j < 4; ++j)
                    acc[i][j] = __builtin_amdgcn_mfma_f32_16x16x32_bf16(a[i], b[j], acc[i][j], 0, 0, 0);
        }
    }

    if (z < 2) {
#pragma unroll
        for (int i = 0; i < 4; ++i)
#pragma unroll
            for (int j = 0; j < 4; ++j)
#pragma unroll
                for (int r = 0; r < 4; ++r) {
                    int m = m0 + wr * 64 + i * 16 + lg * 4 + r;
                    int n = n0 + wc * 64 + j * 16 + l15;
                    int b_ = m >> 11, s = m & (S_LEN - 1);
                    int h = n >> 6, dk = n & 63;
                    Yv[(size_t)z * PSZ +
                       (((size_t)(b_ * NUM_HEADS + h) * S_LEN + s) * D_K + dk)] = f2bf(acc[i][j][r]);
                }
    } else {
        // V: write Vt[bh][dk][s]; 4 consecutive s per fragment -> 8B stores
#pragma unroll
        for (int i = 0; i < 4; ++i)
#pragma unroll
            for (int j = 0; j < 4; ++j) {
                int m = m0 + wr * 64 + i * 16 + lg * 4;   // 4 consecutive s
                int n = n0 + wc * 64 + j * 16 + l15;
                int b_ = m >> 11, s = m & (S_LEN - 1);
                int h = n >> 6, dk = n & 63;
                s16x4 pack;
#pragma unroll
                for (int r = 0; r < 4; ++r) pack[r] = f2bf(acc[i][j][r]);
                *(s16x4*)(Vt + ((size_t)(b_ * NUM_HEADS + h) * D_K + dk) * S_LEN + s) = pack;
            }
    }
}

// ---------------------------------------------------------------------------
// O-projection: 64x64 tile -> 768 blocks (3/CU). out = AO @ Wo^T + bias.
// gload_lds staging into linear LDS (keeps __syncthreads: gload_lds
// completion is vmcnt-tracked, the full drain IS required here).
// ---------------------------------------------------------------------------
__global__ void proj64o(const short* __restrict__ AO, const short* __restrict__ Wt,
                        const float* __restrict__ bias, float* __restrict__ out) {
    __shared__ __align__(16) char As[8192];   // [64][64] bf16 linear
    __shared__ __align__(16) char Bs[8192];
    const int t = threadIdx.x, lane = t & 63, w = t >> 6;
    const int l15 = lane & 15, lg = lane >> 4;
    const int wr = w >> 1, wc = w & 1;
    const int m0 = blockIdx.x * 64, n0 = blockIdx.y * 64;

    const int r8 = t >> 3, c8 = (t & 7) * 8;   // 256 units of 16B cover 32 rows
    f32x4 acc[2][2] = {};
    for (int k0 = 0; k0 < D_MODEL; k0 += 64) {
        __syncthreads();
        {
            gload16(AO + (size_t)(m0 + r8) * D_MODEL + k0 + c8, As + t * 16);
            gload16(AO + (size_t)(m0 + 32 + r8) * D_MODEL + k0 + c8, As + (t + 256) * 16);
            gload16(Wt + (size_t)(n0 + r8) * D_MODEL + k0 + c8, Bs + t * 16);
            gload16(Wt + (size_t)(n0 + 32 + r8) * D_MODEL + k0 + c8, Bs + (t + 256) * 16);
        }
        __syncthreads();
#pragma unroll
        for (int kk = 0; kk < 2; ++kk) {
            const int kb = kk * 64 + lg * 16;
            s16x8 a[2], b[2];
#pragma unroll
            for (int i = 0; i < 2; ++i) {
                a[i] = *(const s16x8*)(As + (wr * 32 + i * 16 + l15) * 128 + kb);
                b[i] = *(const s16x8*)(Bs + (wc * 32 + i * 16 + l15) * 128 + kb);
            }
#pragma unroll
            for (int i = 0; i < 2; ++i)
#pragma unroll
                for (int j = 0; j < 2; ++j)
                    acc[i][j] = __builtin_amdgcn_mfma_f32_16x16x32_bf16(a[i], b[j], acc[i][j], 0, 0, 0);
        }
    }
#pragma unroll
    for (int i = 0; i < 2; ++i)
#pragma unroll
        for (int j = 0; j < 2; ++j)
#pragma unroll
            for (int r = 0; r < 4; ++r) {
                int m = m0 + wr * 32 + i * 16 + lg * 4 + r;
                int n = n0 + wc * 32 + j * 16 + l15;
                __builtin_nontemporal_store(acc[i][j][r] + bias[n],
                                            out + (size_t)m * D_MODEL + n);
            }
}

// ---------------------------------------------------------------------------
// Fused attention — R1 change: ALL main-loop barriers are now LDS-only
// (lgkmcnt(0) + raw s_barrier). __syncthreads drained vmcnt(0) every kt
// iteration, forcing the 16KB/iter attn store burst to fully retire 32x
// per block -> bursty write stream. With ldsbar(), stores stay in flight
// across barriers and retire in the background; the vmcnt FIFO naturally
// gives each store batch one full iteration of slack (staging-load reuse
// waits at vmcnt(4), keeping the current stores airborne).
// ---------------------------------------------------------------------------
#define KS(c) (SMEM + (c) * 8192)
#define VS(c) (SMEM + 16384 + (c) * 8192)
#define PS    (SMEM + 32768)
#define KB(c) (SMEM + (c) * 16384)

__global__ __launch_bounds__(256, 4) void attn_fused(const short* __restrict__ Qp,
                                                     const short* __restrict__ Kp,
                                                     const short* __restrict__ Vt,
                                                     float* __restrict__ attn,
                                                     short* __restrict__ AO) {
    __shared__ __align__(16) char SMEM[40960];

    const int t = threadIdx.x, lane = t & 63, w = t >> 6;
    const int l15 = lane & 15, lg = lane >> 4;
    int wg = blockIdx.x;
    wg = (wg & 7) * 96 + (wg >> 3);   // XCD-chunked: 96 wgs (3 heads) per XCD
    const int q0 = (wg & 31) * 64;
    const int bh = wg >> 5;
    const int b_ = bh / NUM_HEADS, h = bh % NUM_HEADS;
    const short* Qg = Qp + (size_t)bh * S_LEN * D_K;
    const short* Kg = Kp + (size_t)bh * S_LEN * D_K;
    const short* Vg = Vt + (size_t)bh * D_K * S_LEN;
    float* attng = attn + (size_t)bh * S_LEN * S_LEN;
    char* Pw = PS + w * 2048;

    const int r0 = t >> 3, c0 = t & 7;          // this thread's staging slot 0
    const int r1 = (t + 256) >> 3, c1 = t & 7;  // slot 1 (rows 32..63)

    // Q fragments (B-operand) direct from global, invariant across kt
    const int qrow = w * 16 + l15;
    const s16x8 qa = *(const s16x8*)(Qg + (size_t)(q0 + qrow) * D_K + lg * 8);
    const s16x8 qb = *(const s16x8*)(Qg + (size_t)(q0 + qrow) * D_K + 32 + lg * 8);

    // ---- pass 1 prologue: stage K rows 0..127 into KB(0) ----
#pragma unroll
    for (int e = 0; e < 4; ++e) {
        int row = r0 + 32 * e;
        s16x8 kv = *(const s16x8*)(Kg + (size_t)row * D_K + c0 * 8);
        *(s16x8*)(KB(0) + SWZ(row, c0 * 16)) = kv;
    }
    ldsbar();

    // ---- pass 1: Z = row sums of exp2(s'); BK=128, 16 barriers ----
    f32x4 zv = {};
    for (int kt2 = 0; kt2 < 16; ++kt2) {
        const int c = kt2 & 1;
        s16x8 nk[4];
        if (kt2 < 15) {
#pragma unroll
            for (int e = 0; e < 4; ++e)
                nk[e] = *(const s16x8*)(Kg + (size_t)((kt2 + 1) * 128 + r0 + 32 * e) * D_K + c0 * 8);
        }
#pragma unroll
        for (int sub = 0; sub < 2; ++sub)
#pragma unroll
            for (int mf = 0; mf < 4; ++mf) {
                int krow = sub * 64 + mf * 16 + l15;
                s16x8 ka = *(const s16x8*)(KB(c) + SWZ(krow, lg * 16));
                s16x8 kb = *(const s16x8*)(KB(c) + SWZ(krow, 64 + lg * 16));
                f32x4 s4 = {};
                s4 = __builtin_amdgcn_mfma_f32_16x16x32_bf16(ka, qa, s4, 0, 0, 0);
                s4 = __builtin_amdgcn_mfma_f32_16x16x32_bf16(kb, qb, s4, 0, 0, 0);
#pragma unroll
                for (int r = 0; r < 4; ++r) zv[r] += fexp2(s4[r]);
            }
        if (kt2 < 15) {
#pragma unroll
            for (int e = 0; e < 4; ++e)
                *(s16x8*)(KB(c ^ 1) + SWZ(r0 + 32 * e, c0 * 16)) = nk[e];
        }
        ldsbar();
    }
    float z = (zv[0] + zv[1]) + (zv[2] + zv[3]);
    z += __shfl_xor(z, 16);
    z += __shfl_xor(z, 32);
    const float mlz = -__log2f(z);   // fold normalization into MFMA C-input

    // ---- pass 2 prologue: restage K0, V0 ----
    {
        s16x8 k0 = *(const s16x8*)(Kg + (size_t)r0 * D_K + c0 * 8);
        s16x8 k1 = *(const s16x8*)(Kg + (size_t)r1 * D_K + c1 * 8);
        s16x8 v0 = *(const s16x8*)(Vg + (size_t)r0 * S_LEN + c0 * 8);
        s16x8 v1 = *(const s16x8*)(Vg + (size_t)r1 * S_LEN + c1 * 8);
        *(s16x8*)(KS(0) + SWZ(r0, c0 * 16)) = k0;
        *(s16x8*)(KS(0) + SWZ(r1, c1 * 16)) = k1;
        *(s16x8*)(VS(0) + SWZ(r0, c0 * 16)) = v0;
        *(s16x8*)(VS(0) + SWZ(r1, c1 * 16)) = v1;
    }
    ldsbar();

    f32x4 accO[4] = {};
    for (int kt = 0; kt < 32; ++kt) {
        const int c = kt & 1;
        s16x8 nk0, nk1, nv0, nv1;
        if (kt < 31) {
            nk0 = *(const s16x8*)(Kg + (size_t)((kt + 1) * 64 + r0) * D_K + c0 * 8);
            nk1 = *(const s16x8*)(Kg + (size_t)((kt + 1) * 64 + r1) * D_K + c1 * 8);
            nv0 = *(const s16x8*)(Vg + (size_t)r0 * S_LEN + (kt + 1) * 64 + c0 * 8);
            nv1 = *(const s16x8*)(Vg + (size_t)r1 * S_LEN + (kt + 1) * 64 + c1 * 8);
        }
        // QK^T -> probs (normalized via C-init) -> bf16 Pw (per-wave private)
#pragma unroll
        for (int mf = 0; mf < 4; ++mf) {
            int krow = mf * 16 + l15;
            s16x8 ka = *(const s16x8*)(KS(c) + SWZ(krow, lg * 16));
            s16x8 kb = *(const s16x8*)(KS(c) + SWZ(krow, 64 + lg * 16));
            f32x4 s4 = {mlz, mlz, mlz, mlz};
            s4 = __builtin_amdgcn_mfma_f32_16x16x32_bf16(ka, qa, s4, 0, 0, 0);
            s4 = __builtin_amdgcn_mfma_f32_16x16x32_bf16(kb, qb, s4, 0, 0, 0);
            float p0 = fexp2(s4[0]);
            float p1 = fexp2(s4[1]);
            float p2 = fexp2(s4[2]);
            float p3 = fexp2(s4[3]);
            unsigned pk0, pk1;
            asm("v_cvt_pk_bf16_f32 %0, %1, %2" : "=v"(pk0) : "v"(p0), "v"(p1));
            asm("v_cvt_pk_bf16_f32 %0, %1, %2" : "=v"(pk1) : "v"(p2), "v"(p3));
            u32x2 pw2 = {pk0, pk1};
            *(u32x2*)(Pw + SWZ(l15, mf * 32 + lg * 8)) = pw2;
        }
        asm volatile("s_waitcnt lgkmcnt(0)" ::: "memory");
        __builtin_amdgcn_sched_barrier(0);
        // coalesced prob stores: instr i covers rows i*4+lg; 16 lanes sweep a
        // full 256B row -> ~4 contiguous txns/instr. NONTEMPORAL: don't
        // allocate the 403MB stream in L2 (protect K/V residency).
#pragma unroll
        for (int i = 0; i < 4; ++i) {
            int row = i * 4 + lg;
            u32x2 pk = *(const u32x2*)(Pw + SWZ(row, l15 * 8));
            union { unsigned u; float f; } t0, t1, t2, t3;
            t0.u = pk[0] << 16;
            t1.u = pk[0] & 0xFFFF0000u;
            t2.u = pk[1] << 16;
            t3.u = pk[1] & 0xFFFF0000u;
            f32x4 pv = {t0.f, t1.f, t2.f, t3.f};
            __builtin_nontemporal_store(
                pv, (f32x4*)(attng + (size_t)(q0 + w * 16 + row) * S_LEN + kt * 64 + l15 * 4));
        }
        // PV: O[16q x 64d] += P[16q x 64k] @ V^T[64k x 64d]
#pragma unroll
        for (int ks = 0; ks < 2; ++ks) {
            s16x8 ap = *(const s16x8*)(Pw + SWZ(l15, ks * 64 + lg * 16));
#pragma unroll
            for (int df = 0; df < 4; ++df) {
                int vrow = df * 16 + l15;
                s16x8 bv = *(const s16x8*)(VS(c) + SWZ(vrow, ks * 64 + lg * 16));
                accO[df] = __builtin_amdgcn_mfma_f32_16x16x32_bf16(ap, bv, accO[df], 0, 0, 0);
            }
        }
        if (kt < 31) {
            *(s16x8*)(KS(c ^ 1) + SWZ(r0, c0 * 16)) = nk0;
            *(s16x8*)(KS(c ^ 1) + SWZ(r1, c1 * 16)) = nk1;
            *(s16x8*)(VS(c ^ 1) + SWZ(r0, c0 * 16)) = nv0;
            *(s16x8*)(VS(c ^ 1) + SWZ(r1, c1 * 16)) = nv1;
        }
        ldsbar();
    }

#pragma unroll
    for (int df = 0; df < 4; ++df)
#pragma unroll
        for (int r = 0; r < 4; ++r) {
            int srow = q0 + w * 16 + lg * 4 + r;
            AO[((size_t)(b_ * S_LEN + srow)) * D_MODEL + h * D_K + df * 16 + l15] = f2bf(accO[df][r]);
        }
}

// ---------------------------------------------------------------------------
extern "C" void kernel_launch(void* const* d_in, const int* in_sizes, int n_in,
                              void* d_out, int out_size, void* d_ws, size_t ws_size,
                              hipStream_t stream) {
    const float* q = (const float*)d_in[0];
    const float* k = (const float*)d_in[1];
    const float* v = (const float*)d_in[2];
    const float* Wq = (const float*)d_in[3];
    const float* Wk = (const float*)d_in[4];
    const float* Wv = (const float*)d_in[5];
    const float* Wo = (const float*)d_in[6];
    const float* bo = (const float*)d_in[7];

    float* out = (float*)d_out;         // [B][S][D_MODEL] fp32
    float* attn = (float*)d_out + OUT0; // [B][H][S][S] fp32

    // bf16 q/k/v slabs live in the not-yet-written attn region of d_out
    // (18.9 MB << 403 MB; fully dead before attn_fused overwrites it).
    short* Xb = (short*)attn;

    short* wsS = (short*)d_ws;
    short* Wtq = wsS;            // 4 * WSZ  (Wq*0.125*log2e, Wk, Wv, Wo transposed bf16)
    short* Qp = Wtq + 4 * WSZ;   // 2 * PSZ  (Q,K split-head slabs)
    short* Kp = Qp + PSZ;
    short* Vtg = Kp + PSZ;       // PSZ  (V directly in [bh][dk][s] layout)
    short* AO = Vtg + PSZ;       // PSZ

    dim3 blk(256);

    cvt_all<<<dim3(5184), blk, 0, stream>>>(q, k, v, Xb, Wq, Wk, Wv, Wo, Wtq);

    proj128<<<dim3(M_TOT / 128, D_MODEL / 128, 3), blk, 0, stream>>>(Xb, Wtq, Qp, Vtg);

    attn_fused<<<dim3(768), blk, 0, stream>>>(Qp, Kp, Vtg, attn, AO);

    proj64o<<<dim3(M_TOT / 64, D_MODEL / 64), blk, 0, stream>>>(AO, Wtq + 3 * WSZ, bo, out);
}